// Round 19
// baseline (1522.066 us; speedup 1.0000x reference)
//
#include <hip/hip_runtime.h>
#include <hip/hip_bf16.h>
#include <math.h>

// ---- problem constants ----
constexpr int L_   = 2;
constexpr int D_   = 1024;
constexpr int HID_ = 4096;
constexpr int QH_  = 16;
constexpr int KVH_ = 4;
constexpr int V_   = 32000;
constexpr int B_   = 2;
constexpr int S_   = 2048;
constexpr int R_   = 20;
constexpr int HEAD_ = D_ / QH_;   // 64
constexpr int KD_   = KVH_ * HEAD_; // 256
constexpr int QKV_  = D_ + 2 * KD_; // 1536
constexpr int M_    = B_ * S_;    // 4096 tokens
constexpr float INV_ALPHA_ = 1.0f / 32.0f;
constexpr float LOG_STEP_ = 0.3381180865f;  // ln(50000)/32

typedef unsigned short ushort_t;
typedef __attribute__((ext_vector_type(8))) short bf16x8;
typedef __attribute__((ext_vector_type(4))) float f32x4;
typedef __attribute__((address_space(1))) const unsigned int gas_u32;
typedef __attribute__((address_space(3))) unsigned int las_u32;

__device__ __forceinline__ void gload16(const void* g, void* l) {
  __builtin_amdgcn_global_load_lds((gas_u32*)g, (las_u32*)l, 16, 0, 0);
}

__device__ __forceinline__ ushort_t f2bf(float f) {
  union { float f; unsigned int u; } c; c.f = f;
  unsigned int u = c.u + 0x7FFFu + ((c.u >> 16) & 1u);  // RNE
  return (ushort_t)(u >> 16);
}
__device__ __forceinline__ float bflo(unsigned int w) {
  union { unsigned int u; float f; } c; c.u = w << 16; return c.f;
}
__device__ __forceinline__ float bfhi(unsigned int w) {
  union { unsigned int u; float f; } c; c.u = w & 0xFFFF0000u; return c.f;
}

// ---------------- embedding gather ----------------
__global__ __launch_bounds__(256) void k_embed(const int* __restrict__ xs,
                                               const float* __restrict__ emb,
                                               float* __restrict__ x) {
  int i = blockIdx.x * blockDim.x + threadIdx.x;
  int total4 = M_ * D_ / 4;
  if (i >= total4) return;
  int row = i >> 8;
  int c4  = i & 255;
  const float4* src = reinterpret_cast<const float4*>(emb + (size_t)xs[row] * D_) + c4;
  reinterpret_cast<float4*>(x)[i] = *src;
}

// ---------------- RMSNorm (writes bf16) ----------------
__global__ __launch_bounds__(256) void k_rms(const float* __restrict__ x,
                                             const float* __restrict__ scale,
                                             ushort_t* __restrict__ out) {
  int row = blockIdx.x;
  const float* xr = x + (size_t)row * D_;
  float ss = 0.f;
  for (int i = threadIdx.x; i < D_; i += 256) { float v = xr[i]; ss += v * v; }
  for (int off = 32; off > 0; off >>= 1) ss += __shfl_down(ss, off);
  __shared__ float red[5];
  if ((threadIdx.x & 63) == 0) red[threadIdx.x >> 6] = ss;
  __syncthreads();
  if (threadIdx.x == 0)
    red[4] = rsqrtf((red[0] + red[1] + red[2] + red[3]) * (1.0f / D_) + 1e-5f);
  __syncthreads();
  float inv = red[4];
  ushort_t* orow = out + (size_t)row * D_;
  for (int i = threadIdx.x; i < D_; i += 256) orow[i] = f2bf(scale[i] * xr[i] * inv);
}

// ---------------- cast (emb only) ----------------
__global__ __launch_bounds__(256) void k_cast(const float* __restrict__ in,
                                              ushort_t* __restrict__ out, int n8) {
  int i = blockIdx.x * blockDim.x + threadIdx.x;
  if (i >= n8) return;
  const float4* p = reinterpret_cast<const float4*>(in) + i * 2;
  float4 a = p[0], b = p[1];
  ushort_t r[8] = { f2bf(a.x), f2bf(a.y), f2bf(a.z), f2bf(a.w),
                    f2bf(b.x), f2bf(b.y), f2bf(b.z), f2bf(b.w) };
  reinterpret_cast<uint4*>(out)[i] = *reinterpret_cast<uint4*>(r);
}

// transpose+cast: in f32 [K][N] -> out bf16 [N][K]
__global__ __launch_bounds__(256) void k_tcast(const float* __restrict__ in,
                                               ushort_t* __restrict__ out,
                                               int K, int N) {
  __shared__ float t[32][33];
  int n0 = blockIdx.x * 32, k0 = blockIdx.y * 32;
  int c = threadIdx.x & 31, r0 = threadIdx.x >> 5;
#pragma unroll
  for (int rr = 0; rr < 4; ++rr) {
    int r = r0 + rr * 8;
    t[r][c] = in[(size_t)(k0 + r) * N + n0 + c];
  }
  __syncthreads();
#pragma unroll
  for (int rr = 0; rr < 4; ++rr) {
    int r = r0 + rr * 8;
    out[(size_t)(n0 + r) * K + k0 + c] = f2bf(t[c][r]);
  }
}

// concat qkv bias [1536]
__global__ __launch_bounds__(256) void k_qkvbias(const float* __restrict__ bq,
                                                 const float* __restrict__ bk,
                                                 const float* __restrict__ bv,
                                                 float* __restrict__ b) {
  int i = blockIdx.x * 256 + threadIdx.x;
  if (i >= QKV_) return;
  b[i] = i < D_ ? bq[i] : (i < D_ + KD_ ? bk[i - D_] : bv[i - D_ - KD_]);
}

// ---------------- merged K/V prep: RoPE'd K bf16 [bkh][s][64] + V^T bf16 [bkh][64][s] ----
__global__ __launch_bounds__(256) void k_prep(const float* __restrict__ qkv,
                                              ushort_t* __restrict__ Kb,
                                              ushort_t* __restrict__ Vt) {
  if (blockIdx.x < 2048) {
    // RoPE + K prep (pair index)
    int i = blockIdx.x * 256 + threadIdx.x;
    int pi = i & 31;
    int kh = (i >> 5) & 3;
    int s  = (i >> 7) & (S_ - 1);
    int b  = i >> 18;
    float freq = expf(-LOG_STEP_ * (float)pi);
    float ang = (float)s * freq;
    float sn, cs;
    sincosf(ang, &sn, &cs);
    const float* p = qkv + (size_t)(b * S_ + s) * QKV_ + D_ + kh * 64 + 2 * pi;
    float t0 = p[0], t1 = p[1];
    ushort_t* q = Kb + (size_t)((b * KVH_ + kh) * S_ + s) * 64 + 2 * pi;
    q[0] = f2bf(t0 * cs - t1 * sn);
    q[1] = f2bf(t0 * sn + t1 * cs);
  } else {
    // V transpose
    __shared__ float t[32][33];
    int idx = blockIdx.x - 2048;              // 0..1023
    int s0 = (idx & 63) * 32;
    int d0 = ((idx >> 6) & 1) * 32;
    int bkh = idx >> 7;
    int c = threadIdx.x & 31, r0 = threadIdx.x >> 5;
#pragma unroll
    for (int rr = 0; rr < 4; ++rr) {
      int r = r0 + rr * 8;
      t[r][c] = qkv[(size_t)((bkh >> 2) * S_ + s0 + r) * QKV_ + D_ + KD_ + (bkh & 3) * 64 + d0 + c];
    }
    __syncthreads();
#pragma unroll
    for (int rr = 0; rr < 4; ++rr) {
      int r = r0 + rr * 8;
      Vt[(size_t)(bkh * 64 + d0 + r) * S_ + s0 + c] = f2bf(t[c][r]);
    }
  }
}

// ---------------- MFMA flash attention (Q-RoPE fused, KVBLK=128) ----------------
__global__ __launch_bounds__(256) void k_attn3(const float* __restrict__ qkv,
                                               const ushort_t* __restrict__ Kb,
                                               const ushort_t* __restrict__ Vt,
                                               ushort_t* __restrict__ obf) {
  __shared__ ushort_t Ks[128 * 64];    // [key][d],  8 16B-slots/row, swizzled
  __shared__ ushort_t Vs[64 * 128];    // [d][key], 16 16B-slots/row, swizzled
  __shared__ ushort_t Ps[4][16 * 128]; // per-wave P, 16 slots/row, swizzled

  int bid = blockIdx.x;
  int qt = 31 - (bid & 31);          // heavy blocks first
  int qh = (bid >> 5) & 15;
  int b  = bid >> 9;
  int kh = qh >> 2;
  int tid = threadIdx.x;
  int w = tid >> 6, lane = tid & 63;
  int q0 = qt * 64;

  const ushort_t* Kbh = Kb + (size_t)(b * KVH_ + kh) * S_ * 64;
  const ushort_t* Vth = Vt + (size_t)(b * KVH_ + kh) * 64 * S_;

  const int rsel = lane & 15;
  const int g4 = lane >> 4;

  // Q A-frags with fused RoPE, scaled by 1/8
  bf16x8 qa[2];
  {
    int pos = q0 + w * 16 + rsel;
    const float* qp = qkv + (size_t)(b * S_ + pos) * QKV_ + qh * 64 + g4 * 8;
#pragma unroll
    for (int kk = 0; kk < 2; ++kk) {
      float4 f0 = *reinterpret_cast<const float4*>(qp + kk * 32);
      float4 f1 = *reinterpret_cast<const float4*>(qp + kk * 32 + 4);
      float f[8] = {f0.x, f0.y, f0.z, f0.w, f1.x, f1.y, f1.z, f1.w};
      int dbase = g4 * 8 + kk * 32;
      ushort_t tq[8];
#pragma unroll
      for (int p = 0; p < 4; ++p) {
        int pi = (dbase >> 1) + p;
        float freq = expf(-LOG_STEP_ * (float)pi);
        float ang = (float)pos * freq;
        float sn, cs;
        sincosf(ang, &sn, &cs);
        float t0 = f[2 * p], t1 = f[2 * p + 1];
        tq[2 * p]     = f2bf((t0 * cs - t1 * sn) * 0.125f);
        tq[2 * p + 1] = f2bf((t0 * sn + t1 * cs) * 0.125f);
      }
      qa[kk] = *reinterpret_cast<const bf16x8*>(tq);
    }
  }

  f32x4 oacc[4];
#pragma unroll
  for (int j = 0; j < 4; ++j) oacc[j] = {0.f, 0.f, 0.f, 0.f};
  float m[4] = {-1e30f, -1e30f, -1e30f, -1e30f};
  float l[4] = {0.f, 0.f, 0.f, 0.f};

  for (int t0 = 0; t0 < q0 + 64; t0 += 128) {
    // ---- stage K tile: wave w -> rows [w*32, w*32+32), 8 slots/row ----
#pragma unroll
    for (int q = 0; q < 4; ++q) {
      int item = q * 64 + lane;              // 0..255
      int row = w * 32 + (item >> 3);
      int slot = item & 7;
      const char* gk = (const char*)Kbh + (size_t)(t0 + row) * 128 + ((slot ^ (row & 7)) << 4);
      gload16(gk, (char*)Ks + (size_t)w * 4096 + q * 1024);
    }
    // ---- stage V tile: wave w -> rows [w*16, w*16+16), 16 slots/row ----
#pragma unroll
    for (int q = 0; q < 4; ++q) {
      int item = q * 64 + lane;              // 0..255
      int row = w * 16 + (item >> 4);
      int slot = item & 15;
      const char* gv = (const char*)Vth + (size_t)row * (S_ * 2) + (size_t)t0 * 2 + ((slot ^ (row & 7)) << 4);
      gload16(gv, (char*)Vs + (size_t)w * 4096 + q * 1024);
    }
    __syncthreads();

    // ---- S = Q @ K^T (8 key-groups of 16) ----
    f32x4 sacc[8];
#pragma unroll
    for (int j = 0; j < 8; ++j) sacc[j] = {0.f, 0.f, 0.f, 0.f};
#pragma unroll
    for (int kk = 0; kk < 2; ++kk) {
#pragma unroll
      for (int j = 0; j < 8; ++j) {
        int krow = j * 16 + rsel;
        int chunk = kk * 4 + g4;
        bf16x8 kf = *reinterpret_cast<const bf16x8*>(
            &Ks[krow * 64 + ((chunk ^ (krow & 7)) << 3)]);
        sacc[j] = __builtin_amdgcn_mfma_f32_16x16x32_bf16(qa[kk], kf, sacc[j], 0, 0, 0);
      }
    }
    // ---- causal mask (global indices) ----
    if (t0 + 127 > q0) {
#pragma unroll
      for (int j = 0; j < 8; ++j)
#pragma unroll
        for (int e = 0; e < 4; ++e) {
          int keyg = t0 + j * 16 + rsel;
          int qg = q0 + w * 16 + g4 * 4 + e;
          if (keyg > qg) sacc[j][e] = -1e30f;
        }
    }

    // ---- online softmax ----
    float corr[4];
#pragma unroll
    for (int e = 0; e < 4; ++e) {
      float mt = sacc[0][e];
#pragma unroll
      for (int j = 1; j < 8; ++j) mt = fmaxf(mt, sacc[j][e]);
#pragma unroll
      for (int off = 1; off < 16; off <<= 1) mt = fmaxf(mt, __shfl_xor(mt, off));
      float mn = fmaxf(m[e], mt);
      corr[e] = __expf(m[e] - mn);
      m[e] = mn;
    }
    float rs[4] = {0.f, 0.f, 0.f, 0.f};
#pragma unroll
    for (int j = 0; j < 8; ++j)
#pragma unroll
      for (int e = 0; e < 4; ++e) {
        float p = __expf(sacc[j][e] - m[e]);
        sacc[j][e] = p;
        rs[e] += p;
      }
#pragma unroll
    for (int e = 0; e < 4; ++e) {
#pragma unroll
      for (int off = 1; off < 16; off <<= 1) rs[e] += __shfl_xor(rs[e], off);
      l[e] = l[e] * corr[e] + rs[e];
    }
#pragma unroll
    for (int j = 0; j < 4; ++j)
#pragma unroll
      for (int e = 0; e < 4; ++e) oacc[j][e] *= corr[e];

    // ---- P -> LDS (bf16, swizzled, 16 slots/row) ----
#pragma unroll
    for (int j = 0; j < 8; ++j)
#pragma unroll
      for (int e = 0; e < 4; ++e) {
        int prow = g4 * 4 + e;
        int pcol = j * 16 + rsel;
        Ps[w][prow * 128 + (((pcol >> 3) ^ (prow & 7)) << 3) + (pcol & 7)] = f2bf(sacc[j][e]);
      }

    // ---- O += P @ V (4 k-steps of 32 keys) ----
    bf16x8 pa[4];
#pragma unroll
    for (int kk = 0; kk < 4; ++kk) {
      int chunk = kk * 4 + g4;
      pa[kk] = *reinterpret_cast<const bf16x8*>(
          &Ps[w][rsel * 128 + ((chunk ^ (rsel & 7)) << 3)]);
    }
#pragma unroll
    for (int kk = 0; kk < 4; ++kk) {
#pragma unroll
      for (int jd = 0; jd < 4; ++jd) {
        int vrow = jd * 16 + rsel;
        int chunk = kk * 4 + g4;
        bf16x8 vf = *reinterpret_cast<const bf16x8*>(
            &Vs[vrow * 128 + ((chunk ^ (vrow & 7)) << 3)]);
        oacc[jd] = __builtin_amdgcn_mfma_f32_16x16x32_bf16(pa[kk], vf, oacc[jd], 0, 0, 0);
      }
    }
    __syncthreads();
  }

#pragma unroll
  for (int e = 0; e < 4; ++e) {
    int tok = b * S_ + q0 + w * 16 + g4 * 4 + e;
    float inv = 1.f / l[e];
#pragma unroll
    for (int jd = 0; jd < 4; ++jd) {
      int col = qh * 64 + jd * 16 + rsel;
      obf[(size_t)tok * D_ + col] = f2bf(oacc[jd][e] * inv);
    }
  }
}

// ---------------- SiLU-mul (bf16 in, bf16 out) ----------------
__global__ __launch_bounds__(256) void k_silumul(const ushort_t* __restrict__ g1,
                                                 const ushort_t* __restrict__ g2,
                                                 ushort_t* __restrict__ out) {
  int i = blockIdx.x * 256 + threadIdx.x;   // 8-elem chunk
  uint4 a4 = reinterpret_cast<const uint4*>(g1)[i];
  uint4 b4 = reinterpret_cast<const uint4*>(g2)[i];
  unsigned au[4] = {a4.x, a4.y, a4.z, a4.w};
  unsigned bu[4] = {b4.x, b4.y, b4.z, b4.w};
  ushort_t r[8];
#pragma unroll
  for (int q = 0; q < 4; ++q) {
    float a0 = bflo(au[q]), a1 = bfhi(au[q]);
    float b0 = bflo(bu[q]), b1 = bfhi(bu[q]);
    r[2 * q]     = f2bf(a0 * b0 / (1.f + __expf(-b0)));
    r[2 * q + 1] = f2bf(a1 * b1 / (1.f + __expf(-b1)));
  }
  reinterpret_cast<uint4*>(out)[i] = *reinterpret_cast<uint4*>(r);
}

// ---------------- LoRA-A helpers (trA pre-transpose + coalesced bf16 loraA) --------
__global__ __launch_bounds__(256) void k_trA(const float* __restrict__ A,
                                             ushort_t* __restrict__ At, int K) {
  int idx = blockIdx.x * 256 + threadIdx.x;
  if (idx >= K * R_) return;
  int k = idx / R_, r = idx - k * R_;
  At[(size_t)r * K + k] = f2bf(A[idx]);
}

template <int K>
__global__ __launch_bounds__(256) void k_loraA(const ushort_t* __restrict__ hbm,
                                               const ushort_t* __restrict__ At,
                                               const float* __restrict__ ab,
                                               float* __restrict__ u) {
  constexpr int E = K / 64;
  int row = blockIdx.x * 4 + (threadIdx.x >> 6);
  int lane = threadIdx.x & 63;
  float hf[E];
  {
    const uint4* hp = reinterpret_cast<const uint4*>(hbm + (size_t)row * K + lane * E);
#pragma unroll
    for (int i = 0; i < E / 8; ++i) {
      uint4 vv = hp[i];
      unsigned int wsv[4] = {vv.x, vv.y, vv.z, vv.w};
#pragma unroll
      for (int q = 0; q < 4; ++q) {
        hf[i * 8 + q * 2]     = bflo(wsv[q]);
        hf[i * 8 + q * 2 + 1] = bfhi(wsv[q]);
      }
    }
  }
  for (int r = 0; r < R_; ++r) {
    const uint4* ap = reinterpret_cast<const uint4*>(At + (size_t)r * K + lane * E);
    float acc = 0.f;
#pragma unroll
    for (int i = 0; i < E / 8; ++i) {
      uint4 av = ap[i];
      unsigned int wsv[4] = {av.x, av.y, av.z, av.w};
#pragma unroll
      for (int q = 0; q < 4; ++q) {
        acc = fmaf(hf[i * 8 + q * 2], bflo(wsv[q]), acc);
        acc = fmaf(hf[i * 8 + q * 2 + 1], bfhi(wsv[q]), acc);
      }
    }
#pragma unroll
    for (int off = 1; off < 64; off <<= 1) acc += __shfl_xor(acc, off);
    if (lane == 0) u[(size_t)row * R_ + r] = acc + ab[r];
  }
}

// ---------------- bf16 MFMA GEMM #1: 128x128, BK=32, 3-slot ring (QKV/Wo/W3) ----------------
template <bool LORA, bool OBF>
__global__ __launch_bounds__(256) void k_bgemm(const ushort_t* __restrict__ A,
                                               const ushort_t* __restrict__ Bt,
                                               const float* __restrict__ bias,
                                               const float* __restrict__ u,
                                               const float* __restrict__ Bl,
                                               const float* __restrict__ lb,
                                               const float* __restrict__ Cin,
                                               void* __restrict__ Cout,
                                               int M, int N, int K) {
  __shared__ ushort_t lds[3][2][128 * 32];   // 48 KB
  const int tid = threadIdx.x;
  const int lane = tid & 63;
  const int w = tid >> 6;
  const int wr = w >> 1, wc = w & 1;

  unsigned nwg = gridDim.x * gridDim.y;
  unsigned orig = blockIdx.y * gridDim.x + blockIdx.x;
  unsigned qq = nwg >> 3, r8 = nwg & 7;
  unsigned xcd = orig & 7, loc = orig >> 3;
  unsigned swz = (xcd < r8 ? xcd * (qq + 1) : r8 * (qq + 1) + (xcd - r8) * qq) + loc;
  const int bm = (int)(swz / gridDim.x) * 128;
  const int bn = (int)(swz % gridDim.x) * 128;

  f32x4 acc[4][4];
#pragma unroll
  for (int i = 0; i < 4; ++i)
#pragma unroll
    for (int j = 0; j < 4; ++j) acc[i][j] = {0.f, 0.f, 0.f, 0.f};

  const int srow = (lane >> 2);
  const int skcol = (lane & 3) * 8;
  const int nt = K >> 5;

#define STAGE_TILE(kt)                                                          \
  {                                                                             \
    int k0_ = (kt) * 32;                                                        \
    int sl_ = (kt) % 3;                                                         \
    _Pragma("unroll")                                                           \
    for (int q_ = 0; q_ < 2; ++q_) {                                            \
      int c_ = w * 2 + q_;                                                      \
      gload16(A + (size_t)(bm + c_ * 16 + srow) * K + k0_ + skcol,              \
              (char*)&lds[sl_][0][0] + c_ * 1024);                              \
      gload16(Bt + (size_t)(bn + c_ * 16 + srow) * K + k0_ + skcol,             \
              (char*)&lds[sl_][1][0] + c_ * 1024);                              \
    }                                                                           \
  }

  STAGE_TILE(0)
  STAGE_TILE(1)
  asm volatile("s_waitcnt vmcnt(4)\n\ts_barrier" ::: "memory");

  const int koff = (lane >> 4) * 8;
  const int rsel = lane & 15;

  for (int t = 0; t < nt; ++t) {
    if (t + 2 < nt) STAGE_TILE(t + 2)
    const ushort_t* As = &lds[t % 3][0][0];
    const ushort_t* Bs = &lds[t % 3][1][0];
    bf16x8 af[4], bfr[4];
#pragma unroll
    for (int i = 0; i < 4; ++i)
      af[i] = *reinterpret_cast<const bf16x8*>(&As[(wr * 64 + i * 16 + rsel) * 32 + koff]);
#pragma unroll
    for (int j = 0; j < 4; ++j)
      bfr[j] = *reinterpret_cast<const bf16x8*>(&Bs[(wc * 64 + j * 16 + rsel) * 32 + koff]);
    __builtin_amdgcn_s_setprio(1);
#pragma unroll
    for (int i = 0; i < 4; ++i)
#pragma unroll
      for (int j = 0; j < 4; ++j)
        acc[i][j] = __builtin_amdgcn_mfma_f32_16x16x32_bf16(af[i], bfr[j], acc[i][j], 0, 0, 0);
    __builtin_amdgcn_s_setprio(0);
    if (t + 2 < nt) {
      asm volatile("s_waitcnt vmcnt(4)\n\ts_barrier" ::: "memory");
    } else if (t + 1 < nt) {
      asm volatile("s_waitcnt vmcnt(0)\n\ts_barrier" ::: "memory");
    }
  }
#undef STAGE_TILE

  float* Cf = (float*)Cout;
  ushort_t* Cb = (ushort_t*)Cout;

  if constexpr (LORA) {
    asm volatile("s_barrier" ::: "memory");
    float* Us  = (float*)&lds[0][0][0];    // [128][R]
    float* Bls = (float*)&lds[1][0][0];    // [R][128]
    for (int t = tid; t < 128 * R_; t += 256) {
      Us[t] = u[(size_t)bm * R_ + t];
      int rr = t >> 7, nn = t & 127;
      Bls[t] = Bl[(size_t)rr * N + bn + nn];
    }
    __syncthreads();
#pragma unroll
    for (int i = 0; i < 4; ++i) {
      int rl0 = wr * 64 + i * 16 + (lane >> 4) * 4;
#pragma unroll
      for (int e = 0; e < 4; ++e) {
        int rl = rl0 + e;
        float u20[R_];
#pragma unroll
        for (int r = 0; r < R_; ++r) u20[r] = Us[rl * R_ + r];
#pragma unroll
        for (int j = 0; j < 4; ++j) {
          int cl = wc * 64 + j * 16 + (lane & 15);
          float ud = lb[bn + cl];
#pragma unroll
          for (int r = 0; r < R_; ++r) ud = fmaf(u20[r], Bls[r * 128 + cl], ud);
          int row = bm + rl, col = bn + cl;
          float vv = acc[i][j][e] + ud * INV_ALPHA_;
          if constexpr (OBF) {
            Cb[(size_t)row * N + col] = f2bf(vv);
          } else {
            if (Cin) vv += Cin[(size_t)row * N + col];
            Cf[(size_t)row * N + col] = vv;
          }
        }
      }
    }
  } else {
#pragma unroll
    for (int i = 0; i < 4; ++i) {
      int row0 = bm + wr * 64 + i * 16 + (lane >> 4) * 4;
#pragma unroll
      for (int j = 0; j < 4; ++j) {
        int col = bn + wc * 64 + j * 16 + (lane & 15);
        float bv = bias ? bias[col] : 0.f;
#pragma unroll
        for (int e = 0; e < 4; ++e) {
          int row = row0 + e;
          float vv = acc[i][j][e] + bv;
          if constexpr (OBF) {
            Cb[(size_t)row * N + col] = f2bf(vv);
          } else {
            if (Cin) vv += Cin[(size_t)row * N + col];
            Cf[(size_t)row * N + col] = vv;
          }
        }
      }
    }
  }
}

// ---------------- bf16 MFMA GEMM #3: 256x256 tile, BK=64, 8 waves, ring-2 -------
// ldc = C row stride (allows N-chunked launches with full-width C).
template <bool LORA, bool OBF>
__global__ __launch_bounds__(512, 2) void k_bgemm3(const ushort_t* __restrict__ A,
                                                   const ushort_t* __restrict__ Bt,
                                                   const float* __restrict__ bias,
                                                   const float* __restrict__ u,
                                                   const float* __restrict__ Bl,
                                                   const float* __restrict__ lb,
                                                   const float* __restrict__ Cin,
                                                   void* __restrict__ Cout,
                                                   int M, int N, int K, int ldc) {
  __shared__ ushort_t lds[2][32768];   // slot: A[256][64] @0, B[256][64] @16384 (ushorts)
  const int tid = threadIdx.x;
  const int lane = tid & 63;
  const int w = tid >> 6;          // 0..7
  const int wr = w >> 2;           // 0..1 (128-row band)
  const int wc = w & 3;            // 0..3 (64-col band)

  unsigned nwg = gridDim.x * gridDim.y;
  unsigned orig = blockIdx.y * gridDim.x + blockIdx.x;
  unsigned qq = nwg >> 3, r8 = nwg & 7;
  unsigned xcd = orig & 7, loc = orig >> 3;
  unsigned swz = (xcd < r8 ? xcd * (qq + 1) : r8 * (qq + 1) + (xcd - r8) * qq) + loc;
  const int bm = (int)(swz / gridDim.x) * 256;
  const int bn = (int)(swz % gridDim.x) * 256;

  f32x4 acc[8][4];
#pragma unroll
  for (int i = 0; i < 8; ++i)
#pragma unroll
    for (int j = 0; j < 4; ++j) acc[i][j] = {0.f, 0.f, 0.f, 0.f};

  const int srow8 = lane >> 3;                       // row within 8-row chunk
  const int scol  = ((lane & 7) ^ srow8) * 8;        // swizzled source slot (ushorts)
  const int nt = K >> 6;

#define STAGE3(kt)                                                              \
  {                                                                             \
    int k0_ = (kt) << 6;                                                        \
    int sl_ = (kt) & 1;                                                         \
    _Pragma("unroll")                                                           \
    for (int c_ = 0; c_ < 4; ++c_) {                                            \
      int ch = w * 4 + c_;                                                      \
      gload16(A + (size_t)(bm + ch * 8 + srow8) * K + k0_ + scol,               \
              (char*)&lds[sl_][0] + ch * 1024);                                 \
    }                                                                           \
    _Pragma("unroll")                                                           \
    for (int c_ = 0; c_ < 4; ++c_) {                                            \
      int ch = w * 4 + c_;                                                      \
      gload16(Bt + (size_t)(bn + ch * 8 + srow8) * K + k0_ + scol,              \
              (char*)&lds[sl_][16384] + ch * 1024);                             \
    }                                                                           \
  }

  // prologue: tiles 0,1 in flight (16 loads/thread); wait tile0 (8 remain)
  STAGE3(0)
  STAGE3(1)
  asm volatile("s_waitcnt vmcnt(8)\n\ts_barrier" ::: "memory");

  const int rsel = lane & 15;
  const int g4 = lane >> 4;

  for (int t = 0; t < nt; ++t) {
    const ushort_t* As = &lds[t & 1][0];
    const ushort_t* Bs = &lds[t & 1][16384];
#pragma unroll
    for (int kk = 0; kk < 2; ++kk) {
      int slotA = kk * 4 + g4;
      bf16x8 af[8], bfr[4];
#pragma unroll
      for (int fm = 0; fm < 8; ++fm) {
        int row = wr * 128 + fm * 16 + rsel;
        af[fm] = *reinterpret_cast<const bf16x8*>(&As[row * 64 + ((slotA ^ (row & 7)) << 3)]);
      }
#pragma unroll
      for (int fn = 0; fn < 4; ++fn) {
        int row = wc * 64 + fn * 16 + rsel;
        bfr[fn] = *reinterpret_cast<const bf16x8*>(&Bs[row * 64 + ((slotA ^ (row & 7)) << 3)]);
      }
      __builtin_amdgcn_s_setprio(1);
#pragma unroll
      for (int fm = 0; fm < 8; ++fm)
#pragma unroll
        for (int fn = 0; fn < 4; ++fn)
          acc[fm][fn] = __builtin_amdgcn_mfma_f32_16x16x32_bf16(af[fm], bfr[fn], acc[fm][fn], 0, 0, 0);
      __builtin_amdgcn_s_setprio(0);
    }
    // readers of slot t&1 done -> safe to overwrite with tile t+2
    asm volatile("s_barrier" ::: "memory");
    if (t + 2 < nt) {
      STAGE3(t + 2)
      asm volatile("s_waitcnt vmcnt(8)\n\ts_barrier" ::: "memory");   // t+1 landed
    } else if (t + 1 < nt) {
      asm volatile("s_waitcnt vmcnt(0)\n\ts_barrier" ::: "memory");
    }
  }
#undef STAGE3

  float* Cf = (float*)Cout;
  ushort_t* Cb = (ushort_t*)Cout;

  if constexpr (LORA) {
    asm volatile("s_barrier" ::: "memory");   // waves may be skewed after last tile
    float* Us  = (float*)&lds[0][0];    // [256][R] 20 KB
    float* Bls = (float*)&lds[1][0];    // [R][256] 20 KB
    for (int t2 = tid; t2 < 256 * R_; t2 += 512) Us[t2] = u[(size_t)bm * R_ + t2];
    for (int t2 = tid; t2 < R_ * 256; t2 += 512) {
      int rr = t2 >> 8, nn = t2 & 255;
      Bls[t2] = Bl[(size_t)rr * ldc + bn + nn];
    }
    __syncthreads();
#pragma unroll
    for (int fm = 0; fm < 8; ++fm) {
      int rl0 = wr * 128 + fm * 16 + g4 * 4;
#pragma unroll
      for (int e = 0; e < 4; ++e) {
        int rl = rl0 + e;
        float u20[R_];
#pragma unroll
        for (int r = 0; r < R_; ++r) u20[r] = Us[rl * R_ + r];
#pragma unroll
        for (int fn = 0; fn < 4; ++fn) {
          int cl = wc * 64 + fn * 16 + rsel;
          float ud = lb[bn + cl];
#pragma unroll
          for (int r = 0; r < R_; ++r) ud = fmaf(u20[r], Bls[r * 256 + cl], ud);
          int row = bm + rl, col = bn + cl;
          float vv = acc[fm][fn][e] + ud * INV_ALPHA_;
          if constexpr (OBF) {
            Cb[(size_t)row * ldc + col] = f2bf(vv);
          } else {
            if (Cin) vv += Cin[(size_t)row * ldc + col];
            Cf[(size_t)row * ldc + col] = vv;
          }
        }
      }
    }
  } else {
#pragma unroll
    for (int fm = 0; fm < 8; ++fm) {
      int row0 = bm + wr * 128 + fm * 16 + g4 * 4;
#pragma unroll
      for (int fn = 0; fn < 4; ++fn) {
        int col = bn + wc * 64 + fn * 16 + rsel;
        float bv = bias ? bias[col] : 0.f;
#pragma unroll
        for (int e = 0; e < 4; ++e) {
          int row = row0 + e;
          float vv = acc[fm][fn][e] + bv;
          if constexpr (OBF) {
            Cb[(size_t)row * ldc + col] = f2bf(vv);
          } else {
            if (Cin) vv += Cin[(size_t)row * ldc + col];
            Cf[(size_t)row * ldc + col] = vv;
          }
        }
      }
    }
  }
}

static inline void bgemm(hipStream_t st, const ushort_t* A, const ushort_t* Bt,
                         const float* bias, const float* Cin, float* C,
                         int M, int N, int K) {
  dim3 g(N / 128, M / 128);
  k_bgemm<false, false><<<g, 256, 0, st>>>(A, Bt, bias, nullptr, nullptr, nullptr, Cin, C, M, N, K);
}
static inline void bgemm_lora_f32(hipStream_t st, const ushort_t* A, const ushort_t* Bt,
                                  const float* u, const float* Bl, const float* lb,
                                  const float* Cin, float* C, int M, int N, int K) {
  dim3 g(N / 128, M / 128);
  k_bgemm<true, false><<<g, 256, 0, st>>>(A, Bt, nullptr, u, Bl, lb, Cin, C, M, N, K);
}
// vocab: N-chunked launches for true temporal L3 partitioning of B
static inline void bgemm3_chunked(hipStream_t st, const ushort_t* A, const ushort_t* Bt,
                                  float* C, int M, int N, int K, int NCH) {
  int nch = N / NCH;
  for (int c = 0; c < nch; ++c) {
    dim3 g(NCH / 256, M / 256);
    k_bgemm3<false, false><<<g, 512, 0, st>>>(A, Bt + (size_t)(c * NCH) * K, nullptr,
                                              nullptr, nullptr, nullptr, nullptr,
                                              C + (size_t)c * NCH, M, NCH, K, N);
  }
}
static inline void bgemm3_lora_bf(hipStream_t st, const ushort_t* A, const ushort_t* Bt,
                                  const float* u, const float* Bl, const float* lb,
                                  ushort_t* C, int M, int N, int K) {
  dim3 g(N / 256, M / 256);
  k_bgemm3<true, true><<<g, 512, 0, st>>>(A, Bt, nullptr, u, Bl, lb, nullptr, C, M, N, K, N);
}
static inline void tcast(hipStream_t st, const float* in, ushort_t* out, int K, int N) {
  dim3 g(N / 32, K / 32);
  k_tcast<<<g, 256, 0, st>>>(in, out, K, N);
}

extern "C" void kernel_launch(void* const* d_in, const int* in_sizes, int n_in,
                              void* d_out, int out_size, void* d_ws, size_t ws_size,
                              hipStream_t stream) {
  (void)in_sizes; (void)n_in; (void)out_size; (void)ws_size;
  const int*   xs  = (const int*)d_in[0];
  const float* emb = (const float*)d_in[1];
  const float* Wq  = (const float*)d_in[2];
  const float* bq  = (const float*)d_in[3];
  const float* Wk  = (const float*)d_in[4];
  const float* bk  = (const float*)d_in[5];
  const float* Wv  = (const float*)d_in[6];
  const float* bv  = (const float*)d_in[7];
  const float* Wo  = (const float*)d_in[8];
  const float* bo  = (const float*)d_in[9];
  const float* att_scale   = (const float*)d_in[10];
  const float* mlp_scale   = (const float*)d_in[11];
  const float* final_scale = (const float*)d_in[12];
  const float* W1  = (const float*)d_in[13];
  const float* A1  = (const float*)d_in[14];
  const float* a1b = (const float*)d_in[15];
  const float* B1  = (const float*)d_in[16];
  const float* b1b = (const float*)d_in[17];
  const float* W2  = (const float*)d_in[18];
  const float* A2  = (const float*)d_in[19];
  const float* a2b = (const float*)d_in[20];
  const float* B2  = (const float*)d_in[21];
  const float* b2b = (const float*)d_in[22];
  const float* W3  = (const float*)d_in[23];
  const float* A3  = (const float*)d_in[24];
  const float* a3b = (const float*)d_in[25];
  const float* B3  = (const float*)d_in[26];
  const float* b3b = (const float*)d_in[27];
  float* out = (float*)d_out;

  // workspace layout
  float* ws   = (float*)d_ws;
  float* xbuf = ws;                               // M*D f32
  float* qkv  = xbuf + (size_t)M_ * D_;           // M*1536 f32
  float* ubuf = qkv + (size_t)M_ * QKV_;          // M*R f32
  float* qkvb = ubuf + (size_t)M_ * R_;           // 1536 f32
  ushort_t* g1b = (ushort_t*)(qkvb + QKV_);       // M*HID bf16
  ushort_t* g2b = g1b + (size_t)M_ * HID_;        // M*HID bf16
  ushort_t* hb  = g2b + (size_t)M_ * HID_;        // M*HID bf16
  ushort_t* wT  = hb + (size_t)M_ * HID_;         // HID*D bf16
  ushort_t* At  = wT + (size_t)HID_ * D_;         // R*HID bf16
  ushort_t* embT = At + (size_t)R_ * HID_;        // V*D bf16
  // K/V bf16 alias into g1b region (dead during attention)
  ushort_t* Kb = g1b;                             // B*KVH*S*64
  ushort_t* Vt = Kb + (size_t)B_ * KVH_ * S_ * 64;

  k_embed<<<dim3(M_ * D_ / 4 / 256), dim3(256), 0, stream>>>(xs, emb, xbuf);

  for (int l = 0; l < L_; ++l) {
    // ---- attention ----
    k_rms<<<dim3(M_), dim3(256), 0, stream>>>(xbuf, att_scale + (size_t)l * D_, hb);
    // fused QKV weight: wT rows [0,1024)=Wq^T, [1024,1280)=Wk^T, [1280,1536)=Wv^T
    tcast(stream, Wq + (size_t)l * D_ * D_, wT, D_, D_);
    tcast(stream, Wk + (size_t)l * D_ * KD_, wT + (size_t)D_ * D_, D_, KD_);
    tcast(stream, Wv + (size_t)l * D_ * KD_, wT + (size_t)(D_ + KD_) * D_, D_, KD_);
    k_qkvbias<<<dim3(6), dim3(256), 0, stream>>>(bq + (size_t)l * D_, bk + (size_t)l * KD_,
                                                 bv + (size_t)l * KD_, qkvb);
    bgemm(stream, hb, wT, qkvb, nullptr, qkv, M_, QKV_, D_);
    k_prep<<<dim3(3072), dim3(256), 0, stream>>>(qkv, Kb, Vt);
    k_attn3<<<dim3(B_ * QH_ * (S_ / 64)), dim3(256), 0, stream>>>(qkv, Kb, Vt, hb);
    tcast(stream, Wo + (size_t)l * D_ * D_, wT, D_, D_);
    bgemm(stream, hb, wT, bo + (size_t)l * D_, xbuf, xbuf, M_, D_, D_);

    // ---- MLP ----
    k_rms<<<dim3(M_), dim3(256), 0, stream>>>(xbuf, mlp_scale + (size_t)l * D_, hb);
    // lora1
    k_trA<<<dim3((D_ * R_ + 255) / 256), dim3(256), 0, stream>>>(A1 + (size_t)l * D_ * R_, At, D_);
    k_loraA<D_><<<dim3(M_ / 4), dim3(256), 0, stream>>>(hb, At, a1b + (size_t)l * R_, ubuf);
    tcast(stream, W1 + (size_t)l * D_ * HID_, wT, D_, HID_);
    bgemm3_lora_bf(stream, hb, wT, ubuf, B1 + (size_t)l * R_ * HID_, b1b + (size_t)l * HID_,
                   g1b, M_, HID_, D_);
    // lora2
    k_trA<<<dim3((D_ * R_ + 255) / 256), dim3(256), 0, stream>>>(A2 + (size_t)l * D_ * R_, At, D_);
    k_loraA<D_><<<dim3(M_ / 4), dim3(256), 0, stream>>>(hb, At, a2b + (size_t)l * R_, ubuf);
    tcast(stream, W2 + (size_t)l * D_ * HID_, wT, D_, HID_);
    bgemm3_lora_bf(stream, hb, wT, ubuf, B2 + (size_t)l * R_ * HID_, b2b + (size_t)l * HID_,
                   g2b, M_, HID_, D_);
    // m = g1 * silu(g2) -> hb (bf16)
    k_silumul<<<dim3(M_ * HID_ / 8 / 256), dim3(256), 0, stream>>>(g1b, g2b, hb);
    // lora3: x += m@W3 + (u3@B3 + b3b)/32
    k_trA<<<dim3((HID_ * R_ + 255) / 256), dim3(256), 0, stream>>>(A3 + (size_t)l * HID_ * R_, At, HID_);
    k_loraA<HID_><<<dim3(M_ / 4), dim3(256), 0, stream>>>(hb, At, a3b + (size_t)l * R_, ubuf);
    tcast(stream, W3 + (size_t)l * HID_ * D_, wT, HID_, D_);
    bgemm_lora_f32(stream, hb, wT, ubuf, B3 + (size_t)l * R_ * D_, b3b + (size_t)l * D_,
                   xbuf, xbuf, M_, D_, HID_);
  }

  // ---- final norm + vocab projection (256x256 tile, 5 N-chunks of 6400) ----
  k_rms<<<dim3(M_), dim3(256), 0, stream>>>(xbuf, final_scale, hb);
  {
    int n8 = (int)((size_t)V_ * D_ / 8);
    k_cast<<<dim3((n8 + 255) / 256), dim3(256), 0, stream>>>(emb, embT, n8);
  }
  bgemm3_chunked(stream, hb, embT, out, M_, V_, D_, /*NCH=*/6400);
}

// Round 20
// 1454.422 us; speedup vs baseline: 1.0465x; 1.0465x over previous
//
#include <hip/hip_runtime.h>
#include <hip/hip_bf16.h>
#include <math.h>

// ---- problem constants ----
constexpr int L_   = 2;
constexpr int D_   = 1024;
constexpr int HID_ = 4096;
constexpr int QH_  = 16;
constexpr int KVH_ = 4;
constexpr int V_   = 32000;
constexpr int B_   = 2;
constexpr int S_   = 2048;
constexpr int R_   = 20;
constexpr int HEAD_ = D_ / QH_;   // 64
constexpr int KD_   = KVH_ * HEAD_; // 256
constexpr int QKV_  = D_ + 2 * KD_; // 1536
constexpr int M_    = B_ * S_;    // 4096 tokens
constexpr float INV_ALPHA_ = 1.0f / 32.0f;
constexpr float LOG_STEP_ = 0.3381180865f;  // ln(50000)/32

typedef unsigned short ushort_t;
typedef __attribute__((ext_vector_type(8))) short bf16x8;
typedef __attribute__((ext_vector_type(4))) float f32x4;
typedef __attribute__((address_space(1))) const unsigned int gas_u32;
typedef __attribute__((address_space(3))) unsigned int las_u32;

__device__ __forceinline__ void gload16(const void* g, void* l) {
  __builtin_amdgcn_global_load_lds((gas_u32*)g, (las_u32*)l, 16, 0, 0);
}

__device__ __forceinline__ ushort_t f2bf(float f) {
  union { float f; unsigned int u; } c; c.f = f;
  unsigned int u = c.u + 0x7FFFu + ((c.u >> 16) & 1u);  // RNE
  return (ushort_t)(u >> 16);
}
__device__ __forceinline__ float bflo(unsigned int w) {
  union { unsigned int u; float f; } c; c.u = w << 16; return c.f;
}
__device__ __forceinline__ float bfhi(unsigned int w) {
  union { unsigned int u; float f; } c; c.u = w & 0xFFFF0000u; return c.f;
}

// ---------------- embedding gather ----------------
__global__ __launch_bounds__(256) void k_embed(const int* __restrict__ xs,
                                               const float* __restrict__ emb,
                                               float* __restrict__ x) {
  int i = blockIdx.x * blockDim.x + threadIdx.x;
  int total4 = M_ * D_ / 4;
  if (i >= total4) return;
  int row = i >> 8;
  int c4  = i & 255;
  const float4* src = reinterpret_cast<const float4*>(emb + (size_t)xs[row] * D_) + c4;
  reinterpret_cast<float4*>(x)[i] = *src;
}

// ---------------- RMSNorm (writes bf16) ----------------
__global__ __launch_bounds__(256) void k_rms(const float* __restrict__ x,
                                             const float* __restrict__ scale,
                                             ushort_t* __restrict__ out) {
  int row = blockIdx.x;
  const float* xr = x + (size_t)row * D_;
  float ss = 0.f;
  for (int i = threadIdx.x; i < D_; i += 256) { float v = xr[i]; ss += v * v; }
  for (int off = 32; off > 0; off >>= 1) ss += __shfl_down(ss, off);
  __shared__ float red[5];
  if ((threadIdx.x & 63) == 0) red[threadIdx.x >> 6] = ss;
  __syncthreads();
  if (threadIdx.x == 0)
    red[4] = rsqrtf((red[0] + red[1] + red[2] + red[3]) * (1.0f / D_) + 1e-5f);
  __syncthreads();
  float inv = red[4];
  ushort_t* orow = out + (size_t)row * D_;
  for (int i = threadIdx.x; i < D_; i += 256) orow[i] = f2bf(scale[i] * xr[i] * inv);
}

// ---------------- cast (emb only) ----------------
__global__ __launch_bounds__(256) void k_cast(const float* __restrict__ in,
                                              ushort_t* __restrict__ out, int n8) {
  int i = blockIdx.x * blockDim.x + threadIdx.x;
  if (i >= n8) return;
  const float4* p = reinterpret_cast<const float4*>(in) + i * 2;
  float4 a = p[0], b = p[1];
  ushort_t r[8] = { f2bf(a.x), f2bf(a.y), f2bf(a.z), f2bf(a.w),
                    f2bf(b.x), f2bf(b.y), f2bf(b.z), f2bf(b.w) };
  reinterpret_cast<uint4*>(out)[i] = *reinterpret_cast<uint4*>(r);
}

// transpose+cast: in f32 [K][N] -> out bf16 [N][K]
__global__ __launch_bounds__(256) void k_tcast(const float* __restrict__ in,
                                               ushort_t* __restrict__ out,
                                               int K, int N) {
  __shared__ float t[32][33];
  int n0 = blockIdx.x * 32, k0 = blockIdx.y * 32;
  int c = threadIdx.x & 31, r0 = threadIdx.x >> 5;
#pragma unroll
  for (int rr = 0; rr < 4; ++rr) {
    int r = r0 + rr * 8;
    t[r][c] = in[(size_t)(k0 + r) * N + n0 + c];
  }
  __syncthreads();
#pragma unroll
  for (int rr = 0; rr < 4; ++rr) {
    int r = r0 + rr * 8;
    out[(size_t)(n0 + r) * K + k0 + c] = f2bf(t[c][r]);
  }
}

// concat qkv bias [1536]
__global__ __launch_bounds__(256) void k_qkvbias(const float* __restrict__ bq,
                                                 const float* __restrict__ bk,
                                                 const float* __restrict__ bv,
                                                 float* __restrict__ b) {
  int i = blockIdx.x * 256 + threadIdx.x;
  if (i >= QKV_) return;
  b[i] = i < D_ ? bq[i] : (i < D_ + KD_ ? bk[i - D_] : bv[i - D_ - KD_]);
}

// ---------------- merged K/V prep: RoPE'd K bf16 [bkh][s][64] + V^T bf16 [bkh][64][s] ----
__global__ __launch_bounds__(256) void k_prep(const float* __restrict__ qkv,
                                              ushort_t* __restrict__ Kb,
                                              ushort_t* __restrict__ Vt) {
  if (blockIdx.x < 2048) {
    // RoPE + K prep (pair index)
    int i = blockIdx.x * 256 + threadIdx.x;
    int pi = i & 31;
    int kh = (i >> 5) & 3;
    int s  = (i >> 7) & (S_ - 1);
    int b  = i >> 18;
    float freq = expf(-LOG_STEP_ * (float)pi);
    float ang = (float)s * freq;
    float sn, cs;
    sincosf(ang, &sn, &cs);
    const float* p = qkv + (size_t)(b * S_ + s) * QKV_ + D_ + kh * 64 + 2 * pi;
    float t0 = p[0], t1 = p[1];
    ushort_t* q = Kb + (size_t)((b * KVH_ + kh) * S_ + s) * 64 + 2 * pi;
    q[0] = f2bf(t0 * cs - t1 * sn);
    q[1] = f2bf(t0 * sn + t1 * cs);
  } else {
    // V transpose
    __shared__ float t[32][33];
    int idx = blockIdx.x - 2048;              // 0..1023
    int s0 = (idx & 63) * 32;
    int d0 = ((idx >> 6) & 1) * 32;
    int bkh = idx >> 7;
    int c = threadIdx.x & 31, r0 = threadIdx.x >> 5;
#pragma unroll
    for (int rr = 0; rr < 4; ++rr) {
      int r = r0 + rr * 8;
      t[r][c] = qkv[(size_t)((bkh >> 2) * S_ + s0 + r) * QKV_ + D_ + KD_ + (bkh & 3) * 64 + d0 + c];
    }
    __syncthreads();
#pragma unroll
    for (int rr = 0; rr < 4; ++rr) {
      int r = r0 + rr * 8;
      Vt[(size_t)(bkh * 64 + d0 + r) * S_ + s0 + c] = f2bf(t[c][r]);
    }
  }
}

// ---------------- MFMA flash attention (Q-RoPE fused, KVBLK=128) ----------------
__global__ __launch_bounds__(256) void k_attn3(const float* __restrict__ qkv,
                                               const ushort_t* __restrict__ Kb,
                                               const ushort_t* __restrict__ Vt,
                                               ushort_t* __restrict__ obf) {
  __shared__ ushort_t Ks[128 * 64];    // [key][d],  8 16B-slots/row, swizzled
  __shared__ ushort_t Vs[64 * 128];    // [d][key], 16 16B-slots/row, swizzled
  __shared__ ushort_t Ps[4][16 * 128]; // per-wave P, 16 slots/row, swizzled

  int bid = blockIdx.x;
  int qt = 31 - (bid & 31);          // heavy blocks first
  int qh = (bid >> 5) & 15;
  int b  = bid >> 9;
  int kh = qh >> 2;
  int tid = threadIdx.x;
  int w = tid >> 6, lane = tid & 63;
  int q0 = qt * 64;

  const ushort_t* Kbh = Kb + (size_t)(b * KVH_ + kh) * S_ * 64;
  const ushort_t* Vth = Vt + (size_t)(b * KVH_ + kh) * 64 * S_;

  const int rsel = lane & 15;
  const int g4 = lane >> 4;

  // Q A-frags with fused RoPE, scaled by 1/8
  bf16x8 qa[2];
  {
    int pos = q0 + w * 16 + rsel;
    const float* qp = qkv + (size_t)(b * S_ + pos) * QKV_ + qh * 64 + g4 * 8;
#pragma unroll
    for (int kk = 0; kk < 2; ++kk) {
      float4 f0 = *reinterpret_cast<const float4*>(qp + kk * 32);
      float4 f1 = *reinterpret_cast<const float4*>(qp + kk * 32 + 4);
      float f[8] = {f0.x, f0.y, f0.z, f0.w, f1.x, f1.y, f1.z, f1.w};
      int dbase = g4 * 8 + kk * 32;
      ushort_t tq[8];
#pragma unroll
      for (int p = 0; p < 4; ++p) {
        int pi = (dbase >> 1) + p;
        float freq = expf(-LOG_STEP_ * (float)pi);
        float ang = (float)pos * freq;
        float sn, cs;
        sincosf(ang, &sn, &cs);
        float t0 = f[2 * p], t1 = f[2 * p + 1];
        tq[2 * p]     = f2bf((t0 * cs - t1 * sn) * 0.125f);
        tq[2 * p + 1] = f2bf((t0 * sn + t1 * cs) * 0.125f);
      }
      qa[kk] = *reinterpret_cast<const bf16x8*>(tq);
    }
  }

  f32x4 oacc[4];
#pragma unroll
  for (int j = 0; j < 4; ++j) oacc[j] = {0.f, 0.f, 0.f, 0.f};
  float m[4] = {-1e30f, -1e30f, -1e30f, -1e30f};
  float l[4] = {0.f, 0.f, 0.f, 0.f};

  for (int t0 = 0; t0 < q0 + 64; t0 += 128) {
    // ---- stage K tile: wave w -> rows [w*32, w*32+32), 8 slots/row ----
#pragma unroll
    for (int q = 0; q < 4; ++q) {
      int item = q * 64 + lane;              // 0..255
      int row = w * 32 + (item >> 3);
      int slot = item & 7;
      const char* gk = (const char*)Kbh + (size_t)(t0 + row) * 128 + ((slot ^ (row & 7)) << 4);
      gload16(gk, (char*)Ks + (size_t)w * 4096 + q * 1024);
    }
    // ---- stage V tile: wave w -> rows [w*16, w*16+16), 16 slots/row ----
#pragma unroll
    for (int q = 0; q < 4; ++q) {
      int item = q * 64 + lane;              // 0..255
      int row = w * 16 + (item >> 4);
      int slot = item & 15;
      const char* gv = (const char*)Vth + (size_t)row * (S_ * 2) + (size_t)t0 * 2 + ((slot ^ (row & 7)) << 4);
      gload16(gv, (char*)Vs + (size_t)w * 4096 + q * 1024);
    }
    __syncthreads();

    // ---- S = Q @ K^T (8 key-groups of 16) ----
    f32x4 sacc[8];
#pragma unroll
    for (int j = 0; j < 8; ++j) sacc[j] = {0.f, 0.f, 0.f, 0.f};
#pragma unroll
    for (int kk = 0; kk < 2; ++kk) {
#pragma unroll
      for (int j = 0; j < 8; ++j) {
        int krow = j * 16 + rsel;
        int chunk = kk * 4 + g4;
        bf16x8 kf = *reinterpret_cast<const bf16x8*>(
            &Ks[krow * 64 + ((chunk ^ (krow & 7)) << 3)]);
        sacc[j] = __builtin_amdgcn_mfma_f32_16x16x32_bf16(qa[kk], kf, sacc[j], 0, 0, 0);
      }
    }
    // ---- causal mask (global indices) ----
    if (t0 + 127 > q0) {
#pragma unroll
      for (int j = 0; j < 8; ++j)
#pragma unroll
        for (int e = 0; e < 4; ++e) {
          int keyg = t0 + j * 16 + rsel;
          int qg = q0 + w * 16 + g4 * 4 + e;
          if (keyg > qg) sacc[j][e] = -1e30f;
        }
    }

    // ---- online softmax ----
    float corr[4];
#pragma unroll
    for (int e = 0; e < 4; ++e) {
      float mt = sacc[0][e];
#pragma unroll
      for (int j = 1; j < 8; ++j) mt = fmaxf(mt, sacc[j][e]);
#pragma unroll
      for (int off = 1; off < 16; off <<= 1) mt = fmaxf(mt, __shfl_xor(mt, off));
      float mn = fmaxf(m[e], mt);
      corr[e] = __expf(m[e] - mn);
      m[e] = mn;
    }
    float rs[4] = {0.f, 0.f, 0.f, 0.f};
#pragma unroll
    for (int j = 0; j < 8; ++j)
#pragma unroll
      for (int e = 0; e < 4; ++e) {
        float p = __expf(sacc[j][e] - m[e]);
        sacc[j][e] = p;
        rs[e] += p;
      }
#pragma unroll
    for (int e = 0; e < 4; ++e) {
#pragma unroll
      for (int off = 1; off < 16; off <<= 1) rs[e] += __shfl_xor(rs[e], off);
      l[e] = l[e] * corr[e] + rs[e];
    }
#pragma unroll
    for (int j = 0; j < 4; ++j)
#pragma unroll
      for (int e = 0; e < 4; ++e) oacc[j][e] *= corr[e];

    // ---- P -> LDS (bf16, swizzled, 16 slots/row) ----
#pragma unroll
    for (int j = 0; j < 8; ++j)
#pragma unroll
      for (int e = 0; e < 4; ++e) {
        int prow = g4 * 4 + e;
        int pcol = j * 16 + rsel;
        Ps[w][prow * 128 + (((pcol >> 3) ^ (prow & 7)) << 3) + (pcol & 7)] = f2bf(sacc[j][e]);
      }

    // ---- O += P @ V (4 k-steps of 32 keys) ----
    bf16x8 pa[4];
#pragma unroll
    for (int kk = 0; kk < 4; ++kk) {
      int chunk = kk * 4 + g4;
      pa[kk] = *reinterpret_cast<const bf16x8*>(
          &Ps[w][rsel * 128 + ((chunk ^ (rsel & 7)) << 3)]);
    }
#pragma unroll
    for (int kk = 0; kk < 4; ++kk) {
#pragma unroll
      for (int jd = 0; jd < 4; ++jd) {
        int vrow = jd * 16 + rsel;
        int chunk = kk * 4 + g4;
        bf16x8 vf = *reinterpret_cast<const bf16x8*>(
            &Vs[vrow * 128 + ((chunk ^ (vrow & 7)) << 3)]);
        oacc[jd] = __builtin_amdgcn_mfma_f32_16x16x32_bf16(pa[kk], vf, oacc[jd], 0, 0, 0);
      }
    }
    __syncthreads();
  }

#pragma unroll
  for (int e = 0; e < 4; ++e) {
    int tok = b * S_ + q0 + w * 16 + g4 * 4 + e;
    float inv = 1.f / l[e];
#pragma unroll
    for (int jd = 0; jd < 4; ++jd) {
      int col = qh * 64 + jd * 16 + rsel;
      obf[(size_t)tok * D_ + col] = f2bf(oacc[jd][e] * inv);
    }
  }
}

// ---------------- SiLU-mul (bf16 in, bf16 out) ----------------
__global__ __launch_bounds__(256) void k_silumul(const ushort_t* __restrict__ g1,
                                                 const ushort_t* __restrict__ g2,
                                                 ushort_t* __restrict__ out) {
  int i = blockIdx.x * 256 + threadIdx.x;   // 8-elem chunk
  uint4 a4 = reinterpret_cast<const uint4*>(g1)[i];
  uint4 b4 = reinterpret_cast<const uint4*>(g2)[i];
  unsigned au[4] = {a4.x, a4.y, a4.z, a4.w};
  unsigned bu[4] = {b4.x, b4.y, b4.z, b4.w};
  ushort_t r[8];
#pragma unroll
  for (int q = 0; q < 4; ++q) {
    float a0 = bflo(au[q]), a1 = bfhi(au[q]);
    float b0 = bflo(bu[q]), b1 = bfhi(bu[q]);
    r[2 * q]     = f2bf(a0 * b0 / (1.f + __expf(-b0)));
    r[2 * q + 1] = f2bf(a1 * b1 / (1.f + __expf(-b1)));
  }
  reinterpret_cast<uint4*>(out)[i] = *reinterpret_cast<uint4*>(r);
}

// ---------------- LoRA-A helpers (trA pre-transpose + coalesced bf16 loraA) --------
__global__ __launch_bounds__(256) void k_trA(const float* __restrict__ A,
                                             ushort_t* __restrict__ At, int K) {
  int idx = blockIdx.x * 256 + threadIdx.x;
  if (idx >= K * R_) return;
  int k = idx / R_, r = idx - k * R_;
  At[(size_t)r * K + k] = f2bf(A[idx]);
}

template <int K>
__global__ __launch_bounds__(256) void k_loraA(const ushort_t* __restrict__ hbm,
                                               const ushort_t* __restrict__ At,
                                               const float* __restrict__ ab,
                                               float* __restrict__ u) {
  constexpr int E = K / 64;
  int row = blockIdx.x * 4 + (threadIdx.x >> 6);
  int lane = threadIdx.x & 63;
  float hf[E];
  {
    const uint4* hp = reinterpret_cast<const uint4*>(hbm + (size_t)row * K + lane * E);
#pragma unroll
    for (int i = 0; i < E / 8; ++i) {
      uint4 vv = hp[i];
      unsigned int wsv[4] = {vv.x, vv.y, vv.z, vv.w};
#pragma unroll
      for (int q = 0; q < 4; ++q) {
        hf[i * 8 + q * 2]     = bflo(wsv[q]);
        hf[i * 8 + q * 2 + 1] = bfhi(wsv[q]);
      }
    }
  }
  for (int r = 0; r < R_; ++r) {
    const uint4* ap = reinterpret_cast<const uint4*>(At + (size_t)r * K + lane * E);
    float acc = 0.f;
#pragma unroll
    for (int i = 0; i < E / 8; ++i) {
      uint4 av = ap[i];
      unsigned int wsv[4] = {av.x, av.y, av.z, av.w};
#pragma unroll
      for (int q = 0; q < 4; ++q) {
        acc = fmaf(hf[i * 8 + q * 2], bflo(wsv[q]), acc);
        acc = fmaf(hf[i * 8 + q * 2 + 1], bfhi(wsv[q]), acc);
      }
    }
#pragma unroll
    for (int off = 1; off < 64; off <<= 1) acc += __shfl_xor(acc, off);
    if (lane == 0) u[(size_t)row * R_ + r] = acc + ab[r];
  }
}

// ---------------- bf16 MFMA GEMM #1: 128x128, BK=32, 3-slot ring (QKV/Wo/W3) ----------------
template <bool LORA, bool OBF>
__global__ __launch_bounds__(256) void k_bgemm(const ushort_t* __restrict__ A,
                                               const ushort_t* __restrict__ Bt,
                                               const float* __restrict__ bias,
                                               const float* __restrict__ u,
                                               const float* __restrict__ Bl,
                                               const float* __restrict__ lb,
                                               const float* __restrict__ Cin,
                                               void* __restrict__ Cout,
                                               int M, int N, int K) {
  __shared__ ushort_t lds[3][2][128 * 32];   // 48 KB
  const int tid = threadIdx.x;
  const int lane = tid & 63;
  const int w = tid >> 6;
  const int wr = w >> 1, wc = w & 1;

  unsigned nwg = gridDim.x * gridDim.y;
  unsigned orig = blockIdx.y * gridDim.x + blockIdx.x;
  unsigned qq = nwg >> 3, r8 = nwg & 7;
  unsigned xcd = orig & 7, loc = orig >> 3;
  unsigned swz = (xcd < r8 ? xcd * (qq + 1) : r8 * (qq + 1) + (xcd - r8) * qq) + loc;
  const int bm = (int)(swz / gridDim.x) * 128;
  const int bn = (int)(swz % gridDim.x) * 128;

  f32x4 acc[4][4];
#pragma unroll
  for (int i = 0; i < 4; ++i)
#pragma unroll
    for (int j = 0; j < 4; ++j) acc[i][j] = {0.f, 0.f, 0.f, 0.f};

  const int srow = (lane >> 2);
  const int skcol = (lane & 3) * 8;
  const int nt = K >> 5;

#define STAGE_TILE(kt)                                                          \
  {                                                                             \
    int k0_ = (kt) * 32;                                                        \
    int sl_ = (kt) % 3;                                                         \
    _Pragma("unroll")                                                           \
    for (int q_ = 0; q_ < 2; ++q_) {                                            \
      int c_ = w * 2 + q_;                                                      \
      gload16(A + (size_t)(bm + c_ * 16 + srow) * K + k0_ + skcol,              \
              (char*)&lds[sl_][0][0] + c_ * 1024);                              \
      gload16(Bt + (size_t)(bn + c_ * 16 + srow) * K + k0_ + skcol,             \
              (char*)&lds[sl_][1][0] + c_ * 1024);                              \
    }                                                                           \
  }

  STAGE_TILE(0)
  STAGE_TILE(1)
  asm volatile("s_waitcnt vmcnt(4)\n\ts_barrier" ::: "memory");

  const int koff = (lane >> 4) * 8;
  const int rsel = lane & 15;

  for (int t = 0; t < nt; ++t) {
    if (t + 2 < nt) STAGE_TILE(t + 2)
    const ushort_t* As = &lds[t % 3][0][0];
    const ushort_t* Bs = &lds[t % 3][1][0];
    bf16x8 af[4], bfr[4];
#pragma unroll
    for (int i = 0; i < 4; ++i)
      af[i] = *reinterpret_cast<const bf16x8*>(&As[(wr * 64 + i * 16 + rsel) * 32 + koff]);
#pragma unroll
    for (int j = 0; j < 4; ++j)
      bfr[j] = *reinterpret_cast<const bf16x8*>(&Bs[(wc * 64 + j * 16 + rsel) * 32 + koff]);
    __builtin_amdgcn_s_setprio(1);
#pragma unroll
    for (int i = 0; i < 4; ++i)
#pragma unroll
      for (int j = 0; j < 4; ++j)
        acc[i][j] = __builtin_amdgcn_mfma_f32_16x16x32_bf16(af[i], bfr[j], acc[i][j], 0, 0, 0);
    __builtin_amdgcn_s_setprio(0);
    if (t + 2 < nt) {
      asm volatile("s_waitcnt vmcnt(4)\n\ts_barrier" ::: "memory");
    } else if (t + 1 < nt) {
      asm volatile("s_waitcnt vmcnt(0)\n\ts_barrier" ::: "memory");
    }
  }
#undef STAGE_TILE

  float* Cf = (float*)Cout;
  ushort_t* Cb = (ushort_t*)Cout;

  if constexpr (LORA) {
    asm volatile("s_barrier" ::: "memory");
    float* Us  = (float*)&lds[0][0][0];    // [128][R]
    float* Bls = (float*)&lds[1][0][0];    // [R][128]
    for (int t = tid; t < 128 * R_; t += 256) {
      Us[t] = u[(size_t)bm * R_ + t];
      int rr = t >> 7, nn = t & 127;
      Bls[t] = Bl[(size_t)rr * N + bn + nn];
    }
    __syncthreads();
#pragma unroll
    for (int i = 0; i < 4; ++i) {
      int rl0 = wr * 64 + i * 16 + (lane >> 4) * 4;
#pragma unroll
      for (int e = 0; e < 4; ++e) {
        int rl = rl0 + e;
        float u20[R_];
#pragma unroll
        for (int r = 0; r < R_; ++r) u20[r] = Us[rl * R_ + r];
#pragma unroll
        for (int j = 0; j < 4; ++j) {
          int cl = wc * 64 + j * 16 + (lane & 15);
          float ud = lb[bn + cl];
#pragma unroll
          for (int r = 0; r < R_; ++r) ud = fmaf(u20[r], Bls[r * 128 + cl], ud);
          int row = bm + rl, col = bn + cl;
          float vv = acc[i][j][e] + ud * INV_ALPHA_;
          if constexpr (OBF) {
            Cb[(size_t)row * N + col] = f2bf(vv);
          } else {
            if (Cin) vv += Cin[(size_t)row * N + col];
            Cf[(size_t)row * N + col] = vv;
          }
        }
      }
    }
  } else {
#pragma unroll
    for (int i = 0; i < 4; ++i) {
      int row0 = bm + wr * 64 + i * 16 + (lane >> 4) * 4;
#pragma unroll
      for (int j = 0; j < 4; ++j) {
        int col = bn + wc * 64 + j * 16 + (lane & 15);
        float bv = bias ? bias[col] : 0.f;
#pragma unroll
        for (int e = 0; e < 4; ++e) {
          int row = row0 + e;
          float vv = acc[i][j][e] + bv;
          if constexpr (OBF) {
            Cb[(size_t)row * N + col] = f2bf(vv);
          } else {
            if (Cin) vv += Cin[(size_t)row * N + col];
            Cf[(size_t)row * N + col] = vv;
          }
        }
      }
    }
  }
}

// ---------------- bf16 MFMA GEMM #3: 256x256 tile, BK=64, 8 waves, ring-2 -------
template <bool LORA, bool OBF>
__global__ __launch_bounds__(512, 2) void k_bgemm3(const ushort_t* __restrict__ A,
                                                   const ushort_t* __restrict__ Bt,
                                                   const float* __restrict__ bias,
                                                   const float* __restrict__ u,
                                                   const float* __restrict__ Bl,
                                                   const float* __restrict__ lb,
                                                   const float* __restrict__ Cin,
                                                   void* __restrict__ Cout,
                                                   int M, int N, int K) {
  __shared__ ushort_t lds[2][32768];   // slot: A[256][64] @0, B[256][64] @16384 (ushorts)
  const int tid = threadIdx.x;
  const int lane = tid & 63;
  const int w = tid >> 6;          // 0..7
  const int wr = w >> 2;           // 0..1 (128-row band)
  const int wc = w & 3;            // 0..3 (64-col band)

  unsigned nwg = gridDim.x * gridDim.y;
  unsigned orig = blockIdx.y * gridDim.x + blockIdx.x;
  unsigned qq = nwg >> 3, r8 = nwg & 7;
  unsigned xcd = orig & 7, loc = orig >> 3;
  unsigned swz = (xcd < r8 ? xcd * (qq + 1) : r8 * (qq + 1) + (xcd - r8) * qq) + loc;
  const int bm = (int)(swz / gridDim.x) * 256;
  const int bn = (int)(swz % gridDim.x) * 256;

  f32x4 acc[8][4];
#pragma unroll
  for (int i = 0; i < 8; ++i)
#pragma unroll
    for (int j = 0; j < 4; ++j) acc[i][j] = {0.f, 0.f, 0.f, 0.f};

  const int srow8 = lane >> 3;                       // row within 8-row chunk
  const int scol  = ((lane & 7) ^ srow8) * 8;        // swizzled source slot (ushorts)
  const int nt = K >> 6;

#define STAGE3(kt)                                                              \
  {                                                                             \
    int k0_ = (kt) << 6;                                                        \
    int sl_ = (kt) & 1;                                                         \
    _Pragma("unroll")                                                           \
    for (int c_ = 0; c_ < 4; ++c_) {                                            \
      int ch = w * 4 + c_;                                                      \
      gload16(A + (size_t)(bm + ch * 8 + srow8) * K + k0_ + scol,               \
              (char*)&lds[sl_][0] + ch * 1024);                                 \
    }                                                                           \
    _Pragma("unroll")                                                           \
    for (int c_ = 0; c_ < 4; ++c_) {                                            \
      int ch = w * 4 + c_;                                                      \
      gload16(Bt + (size_t)(bn + ch * 8 + srow8) * K + k0_ + scol,              \
              (char*)&lds[sl_][16384] + ch * 1024);                             \
    }                                                                           \
  }

  // prologue: tiles 0,1 in flight (16 loads/thread); wait tile0 (8 remain)
  STAGE3(0)
  STAGE3(1)
  asm volatile("s_waitcnt vmcnt(8)\n\ts_barrier" ::: "memory");

  const int rsel = lane & 15;
  const int g4 = lane >> 4;

  for (int t = 0; t < nt; ++t) {
    const ushort_t* As = &lds[t & 1][0];
    const ushort_t* Bs = &lds[t & 1][16384];
#pragma unroll
    for (int kk = 0; kk < 2; ++kk) {
      int slotA = kk * 4 + g4;
      bf16x8 af[8], bfr[4];
#pragma unroll
      for (int fm = 0; fm < 8; ++fm) {
        int row = wr * 128 + fm * 16 + rsel;
        af[fm] = *reinterpret_cast<const bf16x8*>(&As[row * 64 + ((slotA ^ (row & 7)) << 3)]);
      }
#pragma unroll
      for (int fn = 0; fn < 4; ++fn) {
        int row = wc * 64 + fn * 16 + rsel;
        bfr[fn] = *reinterpret_cast<const bf16x8*>(&Bs[row * 64 + ((slotA ^ (row & 7)) << 3)]);
      }
      __builtin_amdgcn_s_setprio(1);
#pragma unroll
      for (int fm = 0; fm < 8; ++fm)
#pragma unroll
        for (int fn = 0; fn < 4; ++fn)
          acc[fm][fn] = __builtin_amdgcn_mfma_f32_16x16x32_bf16(af[fm], bfr[fn], acc[fm][fn], 0, 0, 0);
      __builtin_amdgcn_s_setprio(0);
    }
    // readers of slot t&1 done -> safe to overwrite with tile t+2
    asm volatile("s_barrier" ::: "memory");
    if (t + 2 < nt) {
      STAGE3(t + 2)
      asm volatile("s_waitcnt vmcnt(8)\n\ts_barrier" ::: "memory");   // t+1 landed
    } else if (t + 1 < nt) {
      asm volatile("s_waitcnt vmcnt(0)\n\ts_barrier" ::: "memory");
    }
  }
#undef STAGE3

  float* Cf = (float*)Cout;
  ushort_t* Cb = (ushort_t*)Cout;

  if constexpr (LORA) {
    asm volatile("s_barrier" ::: "memory");   // waves may be skewed after last tile
    float* Us  = (float*)&lds[0][0];    // [256][R] 20 KB
    float* Bls = (float*)&lds[1][0];    // [R][256] 20 KB
    for (int t2 = tid; t2 < 256 * R_; t2 += 512) Us[t2] = u[(size_t)bm * R_ + t2];
    for (int t2 = tid; t2 < R_ * 256; t2 += 512) {
      int rr = t2 >> 8, nn = t2 & 255;
      Bls[t2] = Bl[(size_t)rr * N + bn + nn];
    }
    __syncthreads();
#pragma unroll
    for (int fm = 0; fm < 8; ++fm) {
      int rl0 = wr * 128 + fm * 16 + g4 * 4;
#pragma unroll
      for (int e = 0; e < 4; ++e) {
        int rl = rl0 + e;
        float u20[R_];
#pragma unroll
        for (int r = 0; r < R_; ++r) u20[r] = Us[rl * R_ + r];
#pragma unroll
        for (int fn = 0; fn < 4; ++fn) {
          int cl = wc * 64 + fn * 16 + rsel;
          float ud = lb[bn + cl];
#pragma unroll
          for (int r = 0; r < R_; ++r) ud = fmaf(u20[r], Bls[r * 256 + cl], ud);
          int row = bm + rl, col = bn + cl;
          float vv = acc[fm][fn][e] + ud * INV_ALPHA_;
          if constexpr (OBF) {
            Cb[(size_t)row * N + col] = f2bf(vv);
          } else {
            if (Cin) vv += Cin[(size_t)row * N + col];
            Cf[(size_t)row * N + col] = vv;
          }
        }
      }
    }
  } else {
#pragma unroll
    for (int fm = 0; fm < 8; ++fm) {
      int row0 = bm + wr * 128 + fm * 16 + g4 * 4;
#pragma unroll
      for (int fn = 0; fn < 4; ++fn) {
        int col = bn + wc * 64 + fn * 16 + rsel;
        float bv = bias ? bias[col] : 0.f;
#pragma unroll
        for (int e = 0; e < 4; ++e) {
          int row = row0 + e;
          float vv = acc[fm][fn][e] + bv;
          if constexpr (OBF) {
            Cb[(size_t)row * N + col] = f2bf(vv);
          } else {
            if (Cin) vv += Cin[(size_t)row * N + col];
            Cf[(size_t)row * N + col] = vv;
          }
        }
      }
    }
  }
}

static inline void bgemm(hipStream_t st, const ushort_t* A, const ushort_t* Bt,
                         const float* bias, const float* Cin, float* C,
                         int M, int N, int K) {
  dim3 g(N / 128, M / 128);
  k_bgemm<false, false><<<g, 256, 0, st>>>(A, Bt, bias, nullptr, nullptr, nullptr, Cin, C, M, N, K);
}
static inline void bgemm_lora_f32(hipStream_t st, const ushort_t* A, const ushort_t* Bt,
                                  const float* u, const float* Bl, const float* lb,
                                  const float* Cin, float* C, int M, int N, int K) {
  dim3 g(N / 128, M / 128);
  k_bgemm<true, false><<<g, 256, 0, st>>>(A, Bt, nullptr, u, Bl, lb, Cin, C, M, N, K);
}
static inline void bgemm3(hipStream_t st, const ushort_t* A, const ushort_t* Bt,
                          const float* bias, const float* Cin, float* C,
                          int M, int N, int K) {
  dim3 g(N / 256, M / 256);
  k_bgemm3<false, false><<<g, 512, 0, st>>>(A, Bt, bias, nullptr, nullptr, nullptr, Cin, C, M, N, K);
}
static inline void bgemm3_lora_bf(hipStream_t st, const ushort_t* A, const ushort_t* Bt,
                                  const float* u, const float* Bl, const float* lb,
                                  ushort_t* C, int M, int N, int K) {
  dim3 g(N / 256, M / 256);
  k_bgemm3<true, true><<<g, 512, 0, st>>>(A, Bt, nullptr, u, Bl, lb, nullptr, C, M, N, K);
}
static inline void tcast(hipStream_t st, const float* in, ushort_t* out, int K, int N) {
  dim3 g(N / 32, K / 32);
  k_tcast<<<g, 256, 0, st>>>(in, out, K, N);
}

extern "C" void kernel_launch(void* const* d_in, const int* in_sizes, int n_in,
                              void* d_out, int out_size, void* d_ws, size_t ws_size,
                              hipStream_t stream) {
  (void)in_sizes; (void)n_in; (void)out_size; (void)ws_size;
  const int*   xs  = (const int*)d_in[0];
  const float* emb = (const float*)d_in[1];
  const float* Wq  = (const float*)d_in[2];
  const float* bq  = (const float*)d_in[3];
  const float* Wk  = (const float*)d_in[4];
  const float* bk  = (const float*)d_in[5];
  const float* Wv  = (const float*)d_in[6];
  const float* bv  = (const float*)d_in[7];
  const float* Wo  = (const float*)d_in[8];
  const float* bo  = (const float*)d_in[9];
  const float* att_scale   = (const float*)d_in[10];
  const float* mlp_scale   = (const float*)d_in[11];
  const float* final_scale = (const float*)d_in[12];
  const float* W1  = (const float*)d_in[13];
  const float* A1  = (const float*)d_in[14];
  const float* a1b = (const float*)d_in[15];
  const float* B1  = (const float*)d_in[16];
  const float* b1b = (const float*)d_in[17];
  const float* W2  = (const float*)d_in[18];
  const float* A2  = (const float*)d_in[19];
  const float* a2b = (const float*)d_in[20];
  const float* B2  = (const float*)d_in[21];
  const float* b2b = (const float*)d_in[22];
  const float* W3  = (const float*)d_in[23];
  const float* A3  = (const float*)d_in[24];
  const float* a3b = (const float*)d_in[25];
  const float* B3  = (const float*)d_in[26];
  const float* b3b = (const float*)d_in[27];
  float* out = (float*)d_out;

  // workspace layout
  float* ws   = (float*)d_ws;
  float* xbuf = ws;                               // M*D f32
  float* qkv  = xbuf + (size_t)M_ * D_;           // M*1536 f32
  float* ubuf = qkv + (size_t)M_ * QKV_;          // M*R f32
  float* qkvb = ubuf + (size_t)M_ * R_;           // 1536 f32
  ushort_t* g1b = (ushort_t*)(qkvb + QKV_);       // M*HID bf16
  ushort_t* g2b = g1b + (size_t)M_ * HID_;        // M*HID bf16
  ushort_t* hb  = g2b + (size_t)M_ * HID_;        // M*HID bf16
  ushort_t* wT  = hb + (size_t)M_ * HID_;         // HID*D bf16
  ushort_t* At  = wT + (size_t)HID_ * D_;         // R*HID bf16
  ushort_t* embT = At + (size_t)R_ * HID_;        // V*D bf16
  // K/V bf16 alias into g1b region (dead during attention)
  ushort_t* Kb = g1b;                             // B*KVH*S*64
  ushort_t* Vt = Kb + (size_t)B_ * KVH_ * S_ * 64;

  k_embed<<<dim3(M_ * D_ / 4 / 256), dim3(256), 0, stream>>>(xs, emb, xbuf);

  for (int l = 0; l < L_; ++l) {
    // ---- attention ----
    k_rms<<<dim3(M_), dim3(256), 0, stream>>>(xbuf, att_scale + (size_t)l * D_, hb);
    // fused QKV weight: wT rows [0,1024)=Wq^T, [1024,1280)=Wk^T, [1280,1536)=Wv^T
    tcast(stream, Wq + (size_t)l * D_ * D_, wT, D_, D_);
    tcast(stream, Wk + (size_t)l * D_ * KD_, wT + (size_t)D_ * D_, D_, KD_);
    tcast(stream, Wv + (size_t)l * D_ * KD_, wT + (size_t)(D_ + KD_) * D_, D_, KD_);
    k_qkvbias<<<dim3(6), dim3(256), 0, stream>>>(bq + (size_t)l * D_, bk + (size_t)l * KD_,
                                                 bv + (size_t)l * KD_, qkvb);
    bgemm(stream, hb, wT, qkvb, nullptr, qkv, M_, QKV_, D_);
    k_prep<<<dim3(3072), dim3(256), 0, stream>>>(qkv, Kb, Vt);
    k_attn3<<<dim3(B_ * QH_ * (S_ / 64)), dim3(256), 0, stream>>>(qkv, Kb, Vt, hb);
    tcast(stream, Wo + (size_t)l * D_ * D_, wT, D_, D_);
    bgemm(stream, hb, wT, bo + (size_t)l * D_, xbuf, xbuf, M_, D_, D_);

    // ---- MLP ----
    k_rms<<<dim3(M_), dim3(256), 0, stream>>>(xbuf, mlp_scale + (size_t)l * D_, hb);
    // lora1
    k_trA<<<dim3((D_ * R_ + 255) / 256), dim3(256), 0, stream>>>(A1 + (size_t)l * D_ * R_, At, D_);
    k_loraA<D_><<<dim3(M_ / 4), dim3(256), 0, stream>>>(hb, At, a1b + (size_t)l * R_, ubuf);
    tcast(stream, W1 + (size_t)l * D_ * HID_, wT, D_, HID_);
    bgemm3_lora_bf(stream, hb, wT, ubuf, B1 + (size_t)l * R_ * HID_, b1b + (size_t)l * HID_,
                   g1b, M_, HID_, D_);
    // lora2
    k_trA<<<dim3((D_ * R_ + 255) / 256), dim3(256), 0, stream>>>(A2 + (size_t)l * D_ * R_, At, D_);
    k_loraA<D_><<<dim3(M_ / 4), dim3(256), 0, stream>>>(hb, At, a2b + (size_t)l * R_, ubuf);
    tcast(stream, W2 + (size_t)l * D_ * HID_, wT, D_, HID_);
    bgemm3_lora_bf(stream, hb, wT, ubuf, B2 + (size_t)l * R_ * HID_, b2b + (size_t)l * HID_,
                   g2b, M_, HID_, D_);
    // m = g1 * silu(g2) -> hb (bf16)
    k_silumul<<<dim3(M_ * HID_ / 8 / 256), dim3(256), 0, stream>>>(g1b, g2b, hb);
    // lora3: x += m@W3 + (u3@B3 + b3b)/32
    k_trA<<<dim3((HID_ * R_ + 255) / 256), dim3(256), 0, stream>>>(A3 + (size_t)l * HID_ * R_, At, HID_);
    k_loraA<HID_><<<dim3(M_ / 4), dim3(256), 0, stream>>>(hb, At, a3b + (size_t)l * R_, ubuf);
    tcast(stream, W3 + (size_t)l * HID_ * D_, wT, HID_, D_);
    bgemm_lora_f32(stream, hb, wT, ubuf, B3 + (size_t)l * R_ * D_, b3b + (size_t)l * D_,
                   xbuf, xbuf, M_, D_, HID_);
  }

  // ---- final norm + vocab projection (256x256 tile, BK=64) ----
  k_rms<<<dim3(M_), dim3(256), 0, stream>>>(xbuf, final_scale, hb);
  {
    int n8 = (int)((size_t)V_ * D_ / 8);
    k_cast<<<dim3((n8 + 255) / 256), dim3(256), 0, stream>>>(emb, embT, n8);
  }
  bgemm3(stream, hb, embT, nullptr, nullptr, out, M_, V_, D_);
}